// Round 1
// baseline (302.364 us; speedup 1.0000x reference)
//
#include <hip/hip_runtime.h>

// Problem: B=32, C=3, H=512, W=512  -> NIMG = 96 flat images
// DWT: cA,cH,cV [96,256,256]; conv1 1->16 3x3 SAME +relu +pool2 -> [96,16,128,128]
// conv2 16->8 3x3 SAME +relu +pool2 -> [96,8,64,64]; conv3 8->4 1x1 -> low
// d_out = low (96*4*64*64 = 1,572,864 f32) ++ high (96*2*65536 = 12,582,912 f32)

// ---------------- Kernel 1: Haar DWT ----------------
// cH/cV written directly into d_out high region: out[img*131072 + {0,65536} + i]
__global__ __launch_bounds__(256) void dwt_kernel(
    const float* __restrict__ x, float* __restrict__ cA, float* __restrict__ outHigh)
{
    int idx = blockIdx.x * 256 + threadIdx.x;      // 96*256*128 threads
    int ox2 = idx & 127;                            // covers out cols 2*ox2, 2*ox2+1
    int oy  = (idx >> 7) & 255;
    int img = idx >> 15;
    const float4 t = *(const float4*)(x + ((img * 512 + 2 * oy) * 512 + 4 * ox2));
    const float4 u = *(const float4*)(x + ((img * 512 + 2 * oy + 1) * 512 + 4 * ox2));
    float2 vA, vH, vV;
    vA.x = (t.x + t.y + u.x + u.y) * 0.5f;
    vH.x = (t.x + t.y - u.x - u.y) * 0.5f;
    vV.x = (t.x - t.y + u.x - u.y) * 0.5f;
    vA.y = (t.z + t.w + u.z + u.w) * 0.5f;
    vH.y = (t.z + t.w - u.z - u.w) * 0.5f;
    vV.y = (t.z - t.w + u.z - u.w) * 0.5f;
    int po = (oy << 8) + 2 * ox2;
    *(float2*)(cA + img * 65536 + po) = vA;
    float* hb = outHigh + img * 131072;
    *(float2*)(hb + po) = vH;
    *(float2*)(hb + 65536 + po) = vV;
}

// ---------------- Kernel 2: conv1 (1->16) + relu + maxpool2 ----------------
// Block: pooled 32x32 tile, all 16 oc. 256 threads, each a 2x2 pooled block.
__global__ __launch_bounds__(256) void conv1_kernel(
    const float* __restrict__ cA, const float* __restrict__ w1,
    const float* __restrict__ b1, float* __restrict__ h1)
{
    __shared__ __align__(16) float tile[66 * 68];   // 66x66 input tile, stride 68
    int img = blockIdx.x >> 4;
    int t   = blockIdx.x & 15;
    int ty = t >> 2, tx = t & 3;                    // 4x4 tiles over pooled 128
    int iy0 = ty * 64 - 1, ix0 = tx * 64 - 1;       // cA-space tile origin
    const float* src = cA + img * 65536;
    for (int i = threadIdx.x; i < 66 * 66; i += 256) {
        int ly = i / 66, lx = i - ly * 66;
        int gy = iy0 + ly, gx = ix0 + lx;
        float v = 0.f;
        if ((unsigned)gy < 256u && (unsigned)gx < 256u) v = src[(gy << 8) + gx];
        tile[ly * 68 + lx] = v;
    }
    __syncthreads();
    int ly2 = threadIdx.x >> 4, lx2 = threadIdx.x & 15;
    float win[6][6];
    {
        const float* base = tile + (ly2 * 4) * 68 + lx2 * 4;   // 16B aligned
        #pragma unroll
        for (int r = 0; r < 6; ++r) {
            float4 p = *(const float4*)(base + r * 68);
            float2 q = *(const float2*)(base + r * 68 + 4);
            win[r][0] = p.x; win[r][1] = p.y; win[r][2] = p.z; win[r][3] = p.w;
            win[r][4] = q.x; win[r][5] = q.y;
        }
    }
    int poy = ty * 32 + ly2 * 2, pox = tx * 32 + lx2 * 2;      // pooled coords
    float* dst = h1 + img * 16 * 128 * 128;
    for (int oc = 0; oc < 16; ++oc) {
        float wk[9];
        #pragma unroll
        for (int k = 0; k < 9; ++k) wk[k] = w1[oc * 9 + k];    // uniform -> s_load
        float bias = b1[oc];
        float acc[4][4];
        #pragma unroll
        for (int py = 0; py < 4; ++py)
            #pragma unroll
            for (int px = 0; px < 4; ++px) {
                float s = bias;
                #pragma unroll
                for (int ky = 0; ky < 3; ++ky)
                    #pragma unroll
                    for (int kx = 0; kx < 3; ++kx)
                        s += win[py + ky][px + kx] * wk[ky * 3 + kx];
                acc[py][px] = fmaxf(s, 0.f);
            }
        #pragma unroll
        for (int r = 0; r < 2; ++r) {
            float2 o;
            o.x = fmaxf(fmaxf(acc[2*r][0], acc[2*r][1]), fmaxf(acc[2*r+1][0], acc[2*r+1][1]));
            o.y = fmaxf(fmaxf(acc[2*r][2], acc[2*r][3]), fmaxf(acc[2*r+1][2], acc[2*r+1][3]));
            *(float2*)(dst + (oc * 128 + poy + r) * 128 + pox) = o;
        }
    }
}

// ---------------- Kernel 3: conv2 (16->8) + relu + maxpool2 ----------------
// Block: pooled 16x16 tile, all 8 oc. Stage ic in chunks of 4 (34x34x4 LDS).
__global__ __launch_bounds__(256) void conv2_kernel(
    const float* __restrict__ h1, const float* __restrict__ w2,
    const float* __restrict__ b2, float* __restrict__ h2)
{
    __shared__ __align__(16) float tile[4 * 34 * 36];   // [ic][34][36]
    int img = blockIdx.x >> 4;
    int t   = blockIdx.x & 15;
    int ty = t >> 2, tx = t & 3;                        // 4x4 tiles over pooled 64
    int iy0 = ty * 32 - 1, ix0 = tx * 32 - 1;           // h1-space origin, 34x34
    int ly = threadIdx.x >> 4, lx = threadIdx.x & 15;
    float acc[8][2][2];
    #pragma unroll
    for (int oc = 0; oc < 8; ++oc)
        #pragma unroll
        for (int r = 0; r < 2; ++r)
            #pragma unroll
            for (int c = 0; c < 2; ++c) acc[oc][r][c] = 0.f;
    const float* src = h1 + img * 16 * 128 * 128;
    for (int cc = 0; cc < 4; ++cc) {
        for (int i = threadIdx.x; i < 4 * 34 * 34; i += 256) {
            int icl = i / 1156;
            int rem = i - icl * 1156;
            int lyy = rem / 34, lxx = rem - lyy * 34;
            int gy = iy0 + lyy, gx = ix0 + lxx;
            float v = 0.f;
            if ((unsigned)gy < 128u && (unsigned)gx < 128u)
                v = src[((cc * 4 + icl) * 128 + gy) * 128 + gx];
            tile[(icl * 34 + lyy) * 36 + lxx] = v;
        }
        __syncthreads();
        #pragma unroll
        for (int icl = 0; icl < 4; ++icl) {
            float win[4][4];
            const float* base = tile + (icl * 34 + ly * 2) * 36 + lx * 2;  // 8B aligned
            #pragma unroll
            for (int r = 0; r < 4; ++r) {
                float2 p = *(const float2*)(base + r * 36);
                float2 q = *(const float2*)(base + r * 36 + 2);
                win[r][0] = p.x; win[r][1] = p.y; win[r][2] = q.x; win[r][3] = q.y;
            }
            int ic = cc * 4 + icl;
            #pragma unroll
            for (int oc = 0; oc < 8; ++oc) {
                const float* wb = w2 + (oc * 16 + ic) * 9;     // uniform -> s_load
                #pragma unroll
                for (int ky = 0; ky < 3; ++ky)
                    #pragma unroll
                    for (int kx = 0; kx < 3; ++kx) {
                        float wv = wb[ky * 3 + kx];
                        #pragma unroll
                        for (int r = 0; r < 2; ++r)
                            #pragma unroll
                            for (int c = 0; c < 2; ++c)
                                acc[oc][r][c] += win[r + ky][c + kx] * wv;
                    }
            }
        }
        __syncthreads();
    }
    int py = ty * 16 + ly, px = tx * 16 + lx;           // pooled coords (64x64)
    float* dst = h2 + img * 8 * 64 * 64;
    #pragma unroll
    for (int oc = 0; oc < 8; ++oc) {
        float bias = b2[oc];
        float m00 = fmaxf(acc[oc][0][0] + bias, 0.f);
        float m01 = fmaxf(acc[oc][0][1] + bias, 0.f);
        float m10 = fmaxf(acc[oc][1][0] + bias, 0.f);
        float m11 = fmaxf(acc[oc][1][1] + bias, 0.f);
        dst[(oc * 64 + py) * 64 + px] = fmaxf(fmaxf(m00, m01), fmaxf(m10, m11));
    }
}

// ---------------- Kernel 4: conv3 (8->4, 1x1) + bias -> low ----------------
__global__ __launch_bounds__(256) void conv3_kernel(
    const float* __restrict__ h2, const float* __restrict__ w3,
    const float* __restrict__ b3, float* __restrict__ outLow)
{
    int idx = blockIdx.x * 256 + threadIdx.x;   // 96*1024 threads (float4 over 4096)
    int img = idx >> 10;
    int p4  = idx & 1023;
    const float* src = h2 + img * 8 * 4096;
    float4 v[8];
    #pragma unroll
    for (int ic = 0; ic < 8; ++ic) v[ic] = *(const float4*)(src + ic * 4096 + p4 * 4);
    float* dst = outLow + img * 4 * 4096;
    #pragma unroll
    for (int oc = 0; oc < 4; ++oc) {
        float b = b3[oc];
        float4 o; o.x = b; o.y = b; o.z = b; o.w = b;
        #pragma unroll
        for (int ic = 0; ic < 8; ++ic) {
            float wv = w3[oc * 8 + ic];          // uniform -> s_load
            o.x += wv * v[ic].x; o.y += wv * v[ic].y;
            o.z += wv * v[ic].z; o.w += wv * v[ic].w;
        }
        *(float4*)(dst + oc * 4096 + p4 * 4) = o;
    }
}

extern "C" void kernel_launch(void* const* d_in, const int* in_sizes, int n_in,
                              void* d_out, int out_size, void* d_ws, size_t ws_size,
                              hipStream_t stream) {
    const float* x  = (const float*)d_in[0];
    const float* w1 = (const float*)d_in[1];
    const float* b1 = (const float*)d_in[2];
    const float* w2 = (const float*)d_in[3];
    const float* b2 = (const float*)d_in[4];
    const float* w3 = (const float*)d_in[5];
    const float* b3 = (const float*)d_in[6];
    float* out     = (float*)d_out;
    float* outLow  = out;                     // 1,572,864 floats
    float* outHigh = out + 1572864;           // 12,582,912 floats

    // Workspace layout (floats): cA [0, 6291456) ; h1 [6291456, 31457280)
    // h2 reuses cA's region (3,145,728 floats needed, cA dead after conv1).
    float* cA = (float*)d_ws;
    float* h1 = cA + 6291456;
    float* h2 = cA;

    dwt_kernel  <<<12288, 256, 0, stream>>>(x, cA, outHigh);
    conv1_kernel<<<1536,  256, 0, stream>>>(cA, w1, b1, h1);
    conv2_kernel<<<1536,  256, 0, stream>>>(h1, w2, b2, h2);
    conv3_kernel<<<384,   256, 0, stream>>>(h2, w3, b3, outLow);
}

// Round 2
// 265.192 us; speedup vs baseline: 1.1402x; 1.1402x over previous
//
#include <hip/hip_runtime.h>

// Problem: B=32, C=3, H=512, W=512 -> NIMG = 96 flat images
// DWT: cA [96,256,256] -> ws; cH/cV -> d_out high region directly.
// Fused: conv1(1->16,3x3,SAME)+relu+pool2 -> conv2(16->8)+relu+pool2 -> conv3(8->4,1x1)
//        all in one kernel; h1/h2 never hit HBM.
// d_out = low (1,572,864 f32) ++ high (12,582,912 f32)

// ---------------- Kernel 1: Haar DWT (float4 in/out) ----------------
__global__ __launch_bounds__(256) void dwt_kernel(
    const float* __restrict__ x, float* __restrict__ cA, float* __restrict__ outHigh)
{
    int idx = blockIdx.x * 256 + threadIdx.x;   // 96*256*64 threads
    int ox4 = idx & 63;                          // 4 output cols (8 input cols)
    int oy  = (idx >> 6) & 255;
    int img = idx >> 14;
    const float* r0 = x + ((img * 512 + 2 * oy) * 512 + 8 * ox4);
    const float* r1 = r0 + 512;
    float4 t0 = *(const float4*)(r0);
    float4 t1 = *(const float4*)(r0 + 4);
    float4 u0 = *(const float4*)(r1);
    float4 u1 = *(const float4*)(r1 + 4);
    float4 vA, vH, vV;
    vA.x = (t0.x + t0.y + u0.x + u0.y) * 0.5f;
    vH.x = (t0.x + t0.y - u0.x - u0.y) * 0.5f;
    vV.x = (t0.x - t0.y + u0.x - u0.y) * 0.5f;
    vA.y = (t0.z + t0.w + u0.z + u0.w) * 0.5f;
    vH.y = (t0.z + t0.w - u0.z - u0.w) * 0.5f;
    vV.y = (t0.z - t0.w + u0.z - u0.w) * 0.5f;
    vA.z = (t1.x + t1.y + u1.x + u1.y) * 0.5f;
    vH.z = (t1.x + t1.y - u1.x - u1.y) * 0.5f;
    vV.z = (t1.x - t1.y + u1.x - u1.y) * 0.5f;
    vA.w = (t1.z + t1.w + u1.z + u1.w) * 0.5f;
    vH.w = (t1.z + t1.w - u1.z - u1.w) * 0.5f;
    vV.w = (t1.z - t1.w + u1.z - u1.w) * 0.5f;
    int po = (oy << 8) + 4 * ox4;
    *(float4*)(cA + img * 65536 + po) = vA;
    float* hb = outHigh + img * 131072;
    *(float4*)(hb + po) = vH;
    *(float4*)(hb + 65536 + po) = vV;
}

// ---------------- Kernel 2: fused conv1+pool -> conv2+pool -> conv3 ----------------
// Block = one (img, 16x16-pooled-output tile). 256 threads, one pooled output each.
// LDS: cA tile 70x70 (stride 72) + h1 chunk [4 ic][34][36]. 39,744 B -> 4 blocks/CU.
__global__ __launch_bounds__(256, 4) void fused_conv_kernel(
    const float* __restrict__ cA,
    const float* __restrict__ w1, const float* __restrict__ b1,
    const float* __restrict__ w2, const float* __restrict__ b2,
    const float* __restrict__ w3, const float* __restrict__ b3,
    float* __restrict__ outLow)
{
    __shared__ __align__(16) float ca[70 * 72];
    __shared__ __align__(16) float h1s[4 * 34 * 36];

    int img = blockIdx.x >> 4;
    int t   = blockIdx.x & 15;
    int ty = t >> 2, tx = t & 3;          // 4x4 tiles over pooled-64 output
    int py0 = ty * 32, px0 = tx * 32;     // conv2 pre-pool tile origin (h1/128 space)
    int hy0 = py0 - 1, hx0 = px0 - 1;     // h1 tile origin (34x34, incl. halo)
    int cy0 = 2 * hy0 - 1, cx0 = 2 * hx0 - 1;  // cA tile origin (70x70)

    // Phase 0: stage cA tile, zero-padded OOB (reproduces conv1 SAME padding)
    const float* src = cA + img * 65536;
    for (int i = threadIdx.x; i < 70 * 70; i += 256) {
        int r = i / 70, c = i - r * 70;
        int gy = cy0 + r, gx = cx0 + c;
        float v = 0.f;
        if ((unsigned)gy < 256u && (unsigned)gx < 256u) v = src[(gy << 8) + gx];
        ca[r * 72 + c] = v;
    }

    int ly = threadIdx.x >> 4, lx = threadIdx.x & 15;  // position in 16x16 pooled tile
    float acc[8][2][2];
    #pragma unroll
    for (int oc = 0; oc < 8; ++oc)
        #pragma unroll
        for (int r = 0; r < 2; ++r)
            #pragma unroll
            for (int c = 0; c < 2; ++c) acc[oc][r][c] = 0.f;

    __syncthreads();

    #pragma unroll 1
    for (int cc = 0; cc < 4; ++cc) {
        // conv1 weights for this 4-oc chunk (uniform -> s_load)
        float wk1[4][9], bb1[4];
        #pragma unroll
        for (int o = 0; o < 4; ++o) {
            #pragma unroll
            for (int k = 0; k < 9; ++k) wk1[o][k] = w1[(cc * 4 + o) * 9 + k];
            bb1[o] = b1[cc * 4 + o];
        }
        if (cc) __syncthreads();   // prev chunk's conv2 reads must finish before overwrite

        // Phase a: build h1 chunk = pool2(relu(conv1)) for 4 output channels, 34x34
        #pragma unroll 1
        for (int k = 0; k < 5; ++k) {
            int i = threadIdx.x + k * 256;
            if (i < 1156) {
                int hy = i / 34, hx = i - hy * 34;
                const float* pb = ca + (2 * hy) * 72 + 2 * hx;
                float patch[4][4];
                #pragma unroll
                for (int r = 0; r < 4; ++r) {
                    float2 a = *(const float2*)(pb + r * 72);
                    float2 b = *(const float2*)(pb + r * 72 + 2);
                    patch[r][0] = a.x; patch[r][1] = a.y;
                    patch[r][2] = b.x; patch[r][3] = b.y;
                }
                bool oob = ((unsigned)(hy0 + hy) >= 128u) | ((unsigned)(hx0 + hx) >= 128u);
                #pragma unroll
                for (int o = 0; o < 4; ++o) {
                    float p00 = 0.f, p01 = 0.f, p10 = 0.f, p11 = 0.f;
                    #pragma unroll
                    for (int ky = 0; ky < 3; ++ky)
                        #pragma unroll
                        for (int kx = 0; kx < 3; ++kx) {
                            float wv = wk1[o][ky * 3 + kx];
                            p00 += patch[ky][kx]         * wv;
                            p01 += patch[ky][kx + 1]     * wv;
                            p10 += patch[ky + 1][kx]     * wv;
                            p11 += patch[ky + 1][kx + 1] * wv;
                        }
                    float m = fmaxf(fmaxf(p00, p01), fmaxf(p10, p11)) + bb1[o];
                    m = fmaxf(m, 0.f);
                    h1s[(o * 34 + hy) * 36 + hx] = oob ? 0.f : m;
                }
            }
        }
        __syncthreads();

        // Phase b: conv2 accumulate over these 4 input channels
        #pragma unroll
        for (int icl = 0; icl < 4; ++icl) {
            float win[4][4];
            const float* base = h1s + (icl * 34 + ly * 2) * 36 + lx * 2;
            #pragma unroll
            for (int r = 0; r < 4; ++r) {
                float2 p = *(const float2*)(base + r * 36);
                float2 q = *(const float2*)(base + r * 36 + 2);
                win[r][0] = p.x; win[r][1] = p.y; win[r][2] = q.x; win[r][3] = q.y;
            }
            int ic = cc * 4 + icl;
            #pragma unroll
            for (int oc = 0; oc < 8; ++oc) {
                const float* wb = w2 + (oc * 16 + ic) * 9;   // uniform -> s_load
                #pragma unroll
                for (int ky = 0; ky < 3; ++ky)
                    #pragma unroll
                    for (int kx = 0; kx < 3; ++kx) {
                        float wv = wb[ky * 3 + kx];
                        #pragma unroll
                        for (int r = 0; r < 2; ++r)
                            #pragma unroll
                            for (int c = 0; c < 2; ++c)
                                acc[oc][r][c] += win[r + ky][c + kx] * wv;
                    }
            }
        }
    }

    // Epilogue: bias + relu + pool2 of conv2, then conv3 (1x1, 8->4)
    float h2v[8];
    #pragma unroll
    for (int oc = 0; oc < 8; ++oc) {
        float m = fmaxf(fmaxf(acc[oc][0][0], acc[oc][0][1]),
                        fmaxf(acc[oc][1][0], acc[oc][1][1]));
        h2v[oc] = fmaxf(m + b2[oc], 0.f);
    }
    float* dst = outLow + img * 16384;
    int pos = (ty * 16 + ly) * 64 + tx * 16 + lx;
    #pragma unroll
    for (int oc3 = 0; oc3 < 4; ++oc3) {
        float s = b3[oc3];
        #pragma unroll
        for (int ic = 0; ic < 8; ++ic) s += w3[oc3 * 8 + ic] * h2v[ic];
        dst[oc3 * 4096 + pos] = s;
    }
}

extern "C" void kernel_launch(void* const* d_in, const int* in_sizes, int n_in,
                              void* d_out, int out_size, void* d_ws, size_t ws_size,
                              hipStream_t stream) {
    const float* x  = (const float*)d_in[0];
    const float* w1 = (const float*)d_in[1];
    const float* b1 = (const float*)d_in[2];
    const float* w2 = (const float*)d_in[3];
    const float* b2 = (const float*)d_in[4];
    const float* w3 = (const float*)d_in[5];
    const float* b3 = (const float*)d_in[6];
    float* out     = (float*)d_out;
    float* outLow  = out;                 // 1,572,864 floats
    float* outHigh = out + 1572864;       // 12,582,912 floats

    float* cA = (float*)d_ws;             // 25.2 MB only

    dwt_kernel       <<<6144, 256, 0, stream>>>(x, cA, outHigh);
    fused_conv_kernel<<<1536, 256, 0, stream>>>(cA, w1, b1, w2, b2, w3, b3, outLow);
}

// Round 4
// 238.851 us; speedup vs baseline: 1.2659x; 1.1103x over previous
//
#include <hip/hip_runtime.h>

// Problem: B=32, C=3, H=512, W=512 -> NIMG = 96 flat images
// ONE kernel: per block (img, 16x16-pooled tile):
//   phase 0: Haar DWT of x -> cA 70x70 tile in LDS (zero-pad OOB); interior
//            64x64 cH/cV written straight to d_out high region.
//   phase a/b (x4 ic-chunks): conv1(1->16)+relu+pool2 -> LDS, conv2(16->8) accum.
//   epilogue: relu+pool2, conv3(8->4,1x1) -> d_out low region.
// h1/h2/cA never touch HBM. d_out = low (1,572,864 f32) ++ high (12,582,912 f32)

__global__ __launch_bounds__(256, 4) void fused_all_kernel(
    const float* __restrict__ x,
    const float* __restrict__ w1, const float* __restrict__ b1,
    const float* __restrict__ w2, const float* __restrict__ b2,
    const float* __restrict__ w3, const float* __restrict__ b3,
    float* __restrict__ outLow, float* __restrict__ outHigh)
{
    __shared__ __align__(16) float ca[70 * 72];      // cA tile, rows stride 72
    __shared__ __align__(16) float h1s[4 * 34 * 36]; // conv1 output chunk

    int img = blockIdx.x >> 4;
    int t   = blockIdx.x & 15;
    int ty = t >> 2, tx = t & 3;               // 4x4 tiles over pooled-64 output
    int hy0 = ty * 32 - 1, hx0 = tx * 32 - 1;  // h1 tile origin (34x34 incl halo)
    int cy0 = ty * 64 - 3, cx0 = tx * 64 - 3;  // cA tile origin (70x70)

    const float* xi = x + img * 262144;        // 512*512 image
    float* hb = outHigh + img * 131072;

    // ---- Phase 0a: interior 64x64 cA (coalesced), cH/cV -> global ----
    // Tile interior = rows/cols 3..66. 1024 tasks of 4 cA points each.
    #pragma unroll
    for (int k = 0; k < 4; ++k) {
        int i = threadIdx.x + k * 256;
        int row = i >> 4, cg = i & 15;
        int gy = ty * 64 + row;                // cA row (always in-bounds)
        int gx = tx * 64 + cg * 4;             // cA col, float4-aligned
        const float* r0 = xi + (2 * gy) * 512 + 2 * gx;
        const float* r1 = r0 + 512;
        float4 t0 = *(const float4*)(r0);
        float4 t1 = *(const float4*)(r0 + 4);
        float4 u0 = *(const float4*)(r1);
        float4 u1 = *(const float4*)(r1 + 4);
        float4 vA, vH, vV;
        vA.x = (t0.x + t0.y + u0.x + u0.y) * 0.5f;
        vH.x = (t0.x + t0.y - u0.x - u0.y) * 0.5f;
        vV.x = (t0.x - t0.y + u0.x - u0.y) * 0.5f;
        vA.y = (t0.z + t0.w + u0.z + u0.w) * 0.5f;
        vH.y = (t0.z + t0.w - u0.z - u0.w) * 0.5f;
        vV.y = (t0.z - t0.w + u0.z - u0.w) * 0.5f;
        vA.z = (t1.x + t1.y + u1.x + u1.y) * 0.5f;
        vH.z = (t1.x + t1.y - u1.x - u1.y) * 0.5f;
        vV.z = (t1.x - t1.y + u1.x - u1.y) * 0.5f;
        vA.w = (t1.z + t1.w + u1.z + u1.w) * 0.5f;
        vH.w = (t1.z + t1.w - u1.z - u1.w) * 0.5f;
        vV.w = (t1.z - t1.w + u1.z - u1.w) * 0.5f;
        int po = (gy << 8) + gx;
        *(float4*)(hb + po) = vH;
        *(float4*)(hb + 65536 + po) = vV;
        float* cp = ca + (row + 3) * 72 + cg * 4 + 3;   // odd offset: scalar stores
        cp[0] = vA.x; cp[1] = vA.y; cp[2] = vA.z; cp[3] = vA.w;
    }

    // ---- Phase 0b: 3-wide halo ring of cA (804 points), vA only ----
    // Ring = rows {0,1,2} + rows {67,68,69} (full width) + middle rows 3..66
    // with cols {0,1,2} and {67,68,69}.
    for (int i = threadIdx.x; i < 804; i += 256) {
        int r, c;
        if (i < 210)      { r = i / 70;              c = i - r * 70; }
        else if (i < 420) { int j = i - 210; r = 67 + j / 70; c = j - (j / 70) * 70; }
        else              { int j = i - 420; r = 3 + j / 6; int k6 = j - (j / 6) * 6;
                            c = (k6 < 3) ? k6 : (64 + k6); }   // {0,1,2,67,68,69}
        int gy = cy0 + r, gx = cx0 + c;
        float v = 0.f;
        if ((unsigned)gy < 256u && (unsigned)gx < 256u) {
            const float* p0 = xi + (2 * gy) * 512 + 2 * gx;
            float2 a = *(const float2*)(p0);
            float2 b = *(const float2*)(p0 + 512);
            v = (a.x + a.y + b.x + b.y) * 0.5f;
        }
        ca[r * 72 + c] = v;
    }

    int ly = threadIdx.x >> 4, lx = threadIdx.x & 15;  // pos in 16x16 pooled tile
    float acc[8][2][2];
    #pragma unroll
    for (int oc = 0; oc < 8; ++oc)
        #pragma unroll
        for (int r = 0; r < 2; ++r)
            #pragma unroll
            for (int c = 0; c < 2; ++c) acc[oc][r][c] = 0.f;

    __syncthreads();

    #pragma unroll 1
    for (int cc = 0; cc < 4; ++cc) {
        // conv1 weights for this 4-oc chunk (uniform -> s_load)
        float wk1[4][9], bb1[4];
        #pragma unroll
        for (int o = 0; o < 4; ++o) {
            #pragma unroll
            for (int k = 0; k < 9; ++k) wk1[o][k] = w1[(cc * 4 + o) * 9 + k];
            bb1[o] = b1[cc * 4 + o];
        }
        if (cc) __syncthreads();   // prev chunk's conv2 reads before overwrite

        // Phase a: h1 chunk = pool2(relu(conv1)), 4 oc, 34x34 (incl conv2 halo)
        #pragma unroll 1
        for (int k = 0; k < 5; ++k) {
            int i = threadIdx.x + k * 256;
            if (i < 1156) {
                int hy = i / 34, hx = i - hy * 34;
                const float* pb = ca + (2 * hy) * 72 + 2 * hx;
                float patch[4][4];
                #pragma unroll
                for (int r = 0; r < 4; ++r) {
                    float2 a = *(const float2*)(pb + r * 72);
                    float2 b = *(const float2*)(pb + r * 72 + 2);
                    patch[r][0] = a.x; patch[r][1] = a.y;
                    patch[r][2] = b.x; patch[r][3] = b.y;
                }
                bool oob = ((unsigned)(hy0 + hy) >= 128u) | ((unsigned)(hx0 + hx) >= 128u);
                #pragma unroll
                for (int o = 0; o < 4; ++o) {
                    float p00 = 0.f, p01 = 0.f, p10 = 0.f, p11 = 0.f;
                    #pragma unroll
                    for (int ky = 0; ky < 3; ++ky)
                        #pragma unroll
                        for (int kx = 0; kx < 3; ++kx) {
                            float wv = wk1[o][ky * 3 + kx];
                            p00 += patch[ky][kx]         * wv;
                            p01 += patch[ky][kx + 1]     * wv;
                            p10 += patch[ky + 1][kx]     * wv;
                            p11 += patch[ky + 1][kx + 1] * wv;
                        }
                    float m = fmaxf(fmaxf(p00, p01), fmaxf(p10, p11)) + bb1[o];
                    m = fmaxf(m, 0.f);
                    h1s[(o * 34 + hy) * 36 + hx] = oob ? 0.f : m;
                }
            }
        }
        __syncthreads();

        // Phase b: conv2 accumulate over these 4 input channels
        #pragma unroll
        for (int icl = 0; icl < 4; ++icl) {
            float win[4][4];
            const float* base = h1s + (icl * 34 + ly * 2) * 36 + lx * 2;
            #pragma unroll
            for (int r = 0; r < 4; ++r) {
                float2 p = *(const float2*)(base + r * 36);
                float2 q = *(const float2*)(base + r * 36 + 2);
                win[r][0] = p.x; win[r][1] = p.y; win[r][2] = q.x; win[r][3] = q.y;
            }
            int ic = cc * 4 + icl;
            #pragma unroll
            for (int oc = 0; oc < 8; ++oc) {
                const float* wb = w2 + (oc * 16 + ic) * 9;   // uniform -> s_load
                #pragma unroll
                for (int ky = 0; ky < 3; ++ky)
                    #pragma unroll
                    for (int kx = 0; kx < 3; ++kx) {
                        float wv = wb[ky * 3 + kx];
                        #pragma unroll
                        for (int r = 0; r < 2; ++r)
                            #pragma unroll
                            for (int c = 0; c < 2; ++c)
                                acc[oc][r][c] += win[r + ky][c + kx] * wv;
                    }
            }
        }
    }

    // Epilogue: bias+relu+pool2 of conv2, then conv3 (1x1, 8->4) -> low
    float h2v[8];
    #pragma unroll
    for (int oc = 0; oc < 8; ++oc) {
        float m = fmaxf(fmaxf(acc[oc][0][0], acc[oc][0][1]),
                        fmaxf(acc[oc][1][0], acc[oc][1][1]));
        h2v[oc] = fmaxf(m + b2[oc], 0.f);
    }
    float* dst = outLow + img * 16384;
    int pos = (ty * 16 + ly) * 64 + tx * 16 + lx;
    #pragma unroll
    for (int oc3 = 0; oc3 < 4; ++oc3) {
        float s = b3[oc3];
        #pragma unroll
        for (int ic = 0; ic < 8; ++ic) s += w3[oc3 * 8 + ic] * h2v[ic];
        dst[oc3 * 4096 + pos] = s;
    }
}

extern "C" void kernel_launch(void* const* d_in, const int* in_sizes, int n_in,
                              void* d_out, int out_size, void* d_ws, size_t ws_size,
                              hipStream_t stream) {
    const float* x  = (const float*)d_in[0];
    const float* w1 = (const float*)d_in[1];
    const float* b1 = (const float*)d_in[2];
    const float* w2 = (const float*)d_in[3];
    const float* b2 = (const float*)d_in[4];
    const float* w3 = (const float*)d_in[5];
    const float* b3 = (const float*)d_in[6];
    float* out     = (float*)d_out;
    float* outLow  = out;                 // 1,572,864 floats
    float* outHigh = out + 1572864;       // 12,582,912 floats

    fused_all_kernel<<<1536, 256, 0, stream>>>(x, w1, b1, w2, b2, w3, b3,
                                               outLow, outHigh);
}